// Round 7
// baseline (272.522 us; speedup 1.0000x reference)
//
#include <hip/hip_runtime.h>

#define DIM 1024
#define NHEADS 16
#define HD 64
#define NSEQ 2048
#define MROWS 4096          // B*N
#define QKV_LD 3072

typedef __attribute__((ext_vector_type(8))) short short8;
typedef __attribute__((ext_vector_type(4))) short short4v;
typedef __attribute__((ext_vector_type(4))) float f32x4;

typedef __attribute__((address_space(1))) void gvoid_t;
typedef __attribute__((address_space(3))) void lvoid_t;

#if __has_builtin(__builtin_amdgcn_exp2f)
#define EXP2(x) __builtin_amdgcn_exp2f(x)
#else
#define EXP2(x) exp2f(x)
#endif

// K=16 bf16 MFMA: builtin name varies across ROCm versions; asm fallback.
#if __has_builtin(__builtin_amdgcn_mfma_f32_16x16x16_bf16)
#define MFMA16(a, b, c) __builtin_amdgcn_mfma_f32_16x16x16_bf16(a, b, c, 0, 0, 0)
#elif __has_builtin(__builtin_amdgcn_mfma_f32_16x16x16bf16_1k)
#define MFMA16(a, b, c) __builtin_amdgcn_mfma_f32_16x16x16bf16_1k(a, b, c, 0, 0, 0)
#else
static __device__ __forceinline__ f32x4 mfma16_asm(short4v a, short4v b, f32x4 c) {
  __asm__("v_mfma_f32_16x16x16_bf16 %0, %1, %2, %0" : "+v"(c) : "v"(a), "v"(b));
  return c;
}
#define MFMA16(a, b, c) mfma16_asm(a, b, c)
#endif

#define MFMA32(a, b, c) __builtin_amdgcn_mfma_f32_16x16x32_bf16(a, b, c, 0, 0, 0)

// exp2 arg scale: HEAD_DIM^-0.5 * log2(e)  (folded into Q at GEMM epilogue)
#define EXP_SCALE 0.18033688011112042f

__device__ __forceinline__ unsigned short f2bf(float f) {
  unsigned int u = __builtin_bit_cast(unsigned int, f);
  u += 0x7FFFu + ((u >> 16) & 1u);
  return (unsigned short)(u >> 16);
}

// async global->LDS, 16B per lane; LDS dst = wave-uniform base + lane*16
__device__ __forceinline__ void gl_lds16(const void* g, void* l) {
  __builtin_amdgcn_global_load_lds((gvoid_t*)g, (lvoid_t*)l, 16, 0, 0);
}

// ---------------------------------------------------------------------------
// Kernel 1: cast x (4M), qkv_w (3M), proj_w (1M) fp32 -> bf16. 2M float4 groups.
// ---------------------------------------------------------------------------
__global__ __launch_bounds__(256) void cast_bf16_3(
    const float* __restrict__ x, const float* __restrict__ wq,
    const float* __restrict__ wp,
    unsigned short* __restrict__ xb, unsigned short* __restrict__ wqb,
    unsigned short* __restrict__ wpb)
{
  int g = blockIdx.x * 256 + threadIdx.x;   // 0 .. 2097151
  const float* src;
  unsigned short* dst;
  if (g < 1048576)            { src = x  + (size_t)g * 4;              dst = xb  + (size_t)g * 4; }
  else if (g < 1048576 + 786432) { int t = g - 1048576; src = wq + (size_t)t * 4; dst = wqb + (size_t)t * 4; }
  else                        { int t = g - 1048576 - 786432; src = wp + (size_t)t * 4; dst = wpb + (size_t)t * 4; }
  float4 v = *(const float4*)src;
  ushort4 o;
  o.x = f2bf(v.x); o.y = f2bf(v.y); o.z = f2bf(v.z); o.w = f2bf(v.w);
  *(ushort4*)dst = o;
}

// ---------------------------------------------------------------------------
// Kernel 2: NT GEMM, 128x128x32 tile. mode 1: bf16 Q/K -> oq (ld 3072),
// Q columns pre-scaled by EXP_SCALE; V -> key-tiled V^T vt2[bh][n>>4][d][n&15].
// ---------------------------------------------------------------------------
__global__ __launch_bounds__(256) void gemm_nt(
    const unsigned short* __restrict__ A,
    const unsigned short* __restrict__ Bw,
    const float* __restrict__ bias,
    int K, int mode,
    unsigned short* __restrict__ oq,
    unsigned short* __restrict__ ovt,
    float* __restrict__ of)
{
  __shared__ unsigned short As[128 * 32];
  __shared__ unsigned short Bs[128 * 32];

  const int tid  = threadIdx.x;
  const int wave = tid >> 6, lane = tid & 63;
  const int quad = lane >> 4, l15 = lane & 15;
  const int mblk = blockIdx.x * 128;
  const int nblk = blockIdx.y * 128;
  const int wrow = (wave >> 1) * 64, wcol = (wave & 1) * 64;

  f32x4 acc[4][4] = {};

  const int sr = lane >> 2;                 // row within 16-row chunk
  const int sq = (lane & 3) ^ (sr & 3);     // swizzled k-chunk for this lane
  const unsigned short* aBase = A  + (size_t)(mblk + wave * 32 + sr) * K + sq * 8;
  const unsigned short* bBase = Bw + (size_t)(nblk + wave * 32 + sr) * K + sq * 8;

  for (int k0 = 0; k0 < K; k0 += 32) {
    __syncthreads();
    gl_lds16(aBase + k0,          As + (wave * 32) * 32);
    gl_lds16(aBase + 16 * K + k0, As + (wave * 32 + 16) * 32);
    gl_lds16(bBase + k0,          Bs + (wave * 32) * 32);
    gl_lds16(bBase + 16 * K + k0, Bs + (wave * 32 + 16) * 32);
    __syncthreads();

    short8 af[4], bf8[4];
#pragma unroll
    for (int mt = 0; mt < 4; ++mt) {
      int row = wrow + mt * 16 + l15;
      af[mt] = *(const short8*)(As + row * 32 + ((quad ^ (row & 3)) * 8));
    }
#pragma unroll
    for (int nt = 0; nt < 4; ++nt) {
      int row = wcol + nt * 16 + l15;
      bf8[nt] = *(const short8*)(Bs + row * 32 + ((quad ^ (row & 3)) * 8));
    }
#pragma unroll
    for (int mt = 0; mt < 4; ++mt)
#pragma unroll
      for (int nt = 0; nt < 4; ++nt)
        acc[mt][nt] = MFMA32(af[mt], bf8[nt], acc[mt][nt]);
  }

  float bv[4];
#pragma unroll
  for (int nt = 0; nt < 4; ++nt) bv[nt] = bias[nblk + wcol + nt * 16 + l15];

  if (mode == 0) {
#pragma unroll
    for (int mt = 0; mt < 4; ++mt) {
      int row0 = mblk + wrow + mt * 16 + quad * 4;
#pragma unroll
      for (int nt = 0; nt < 4; ++nt) {
        int col = nblk + wcol + nt * 16 + l15;
#pragma unroll
        for (int r = 0; r < 4; ++r)
          of[(size_t)(row0 + r) * DIM + col] = acc[mt][nt][r] + bv[nt];
      }
    }
  } else if (nblk < 2048) {
    // Q (pre-scaled by EXP_SCALE) or K block -> qkv buffer, bf16
    const float qs = (nblk < 1024) ? EXP_SCALE : 1.0f;
#pragma unroll
    for (int mt = 0; mt < 4; ++mt) {
      int row0 = mblk + wrow + mt * 16 + quad * 4;
#pragma unroll
      for (int nt = 0; nt < 4; ++nt) {
        int col = nblk + wcol + nt * 16 + l15;
#pragma unroll
        for (int r = 0; r < 4; ++r)
          oq[(size_t)(row0 + r) * QKV_LD + col] = f2bf((acc[mt][nt][r] + bv[nt]) * qs);
      }
    }
  } else {
    // V -> key-tiled transposed buffer: vt2[bh][n>>4][d][n&15]
#pragma unroll
    for (int mt = 0; mt < 4; ++mt) {
      int row0 = mblk + wrow + mt * 16 + quad * 4;
      int n0 = row0 & (NSEQ - 1);
      int bb = row0 >> 11;
#pragma unroll
      for (int nt = 0; nt < 4; ++nt) {
        int colr = (nblk - 2048) + wcol + nt * 16 + l15;
        int bh = bb * NHEADS + (colr >> 6);
        int d  = colr & 63;
        ushort4 pk;
        pk.x = f2bf(acc[mt][nt][0] + bv[nt]);
        pk.y = f2bf(acc[mt][nt][1] + bv[nt]);
        pk.z = f2bf(acc[mt][nt][2] + bv[nt]);
        pk.w = f2bf(acc[mt][nt][3] + bv[nt]);
        *(ushort4*)(ovt + (size_t)bh * 131072 + (n0 >> 4) * 1024 + d * 16 + (n0 & 15)) = pk;
      }
    }
  }
}

// ---------------------------------------------------------------------------
// Kernel 4: NT GEMM for proj: 64(M)x128(N)x32 tile -> 512 blocks (2/CU).
// ---------------------------------------------------------------------------
__global__ __launch_bounds__(256) void gemm_nt64(
    const unsigned short* __restrict__ A,
    const unsigned short* __restrict__ Bw,
    const float* __restrict__ bias,
    int K,
    float* __restrict__ of)
{
  __shared__ unsigned short As[64 * 32];
  __shared__ unsigned short Bs[128 * 32];

  const int tid  = threadIdx.x;
  const int wave = tid >> 6, lane = tid & 63;
  const int quad = lane >> 4, l15 = lane & 15;
  const int mblk = blockIdx.x * 64;
  const int nblk = blockIdx.y * 128;
  const int wrow = (wave >> 1) * 32, wcol = (wave & 1) * 64;

  f32x4 acc[2][4] = {};

  const int sr = lane >> 2;
  const int sq = (lane & 3) ^ (sr & 3);
  const unsigned short* aBase = A  + (size_t)(mblk + wave * 16 + sr) * K + sq * 8;
  const unsigned short* bBase = Bw + (size_t)(nblk + wave * 32 + sr) * K + sq * 8;

  for (int k0 = 0; k0 < K; k0 += 32) {
    __syncthreads();
    gl_lds16(aBase + k0,          As + (wave * 16) * 32);
    gl_lds16(bBase + k0,          Bs + (wave * 32) * 32);
    gl_lds16(bBase + 16 * K + k0, Bs + (wave * 32 + 16) * 32);
    __syncthreads();

    short8 af[2], bf8[4];
#pragma unroll
    for (int mt = 0; mt < 2; ++mt) {
      int row = wrow + mt * 16 + l15;
      af[mt] = *(const short8*)(As + row * 32 + ((quad ^ (row & 3)) * 8));
    }
#pragma unroll
    for (int nt = 0; nt < 4; ++nt) {
      int row = wcol + nt * 16 + l15;
      bf8[nt] = *(const short8*)(Bs + row * 32 + ((quad ^ (row & 3)) * 8));
    }
#pragma unroll
    for (int mt = 0; mt < 2; ++mt)
#pragma unroll
      for (int nt = 0; nt < 4; ++nt)
        acc[mt][nt] = MFMA32(af[mt], bf8[nt], acc[mt][nt]);
  }

  float bv[4];
#pragma unroll
  for (int nt = 0; nt < 4; ++nt) bv[nt] = bias[nblk + wcol + nt * 16 + l15];

#pragma unroll
  for (int mt = 0; mt < 2; ++mt) {
    int row0 = mblk + wrow + mt * 16 + quad * 4;
#pragma unroll
    for (int nt = 0; nt < 4; ++nt) {
      int col = nblk + wcol + nt * 16 + l15;
#pragma unroll
      for (int r = 0; r < 4; ++r)
        of[(size_t)(row0 + r) * DIM + col] = acc[mt][nt][r] + bv[nt];
    }
  }
}

// ---------------------------------------------------------------------------
// Kernel 3: fused attention, key-split across waves, NO LDS in the K-loop.
// Block = (b,h) x 64 q. Wave w owns keys {t*64 + w*16 .. +15} at step t.
// K-frags (m=key=l15, k=d) and V^T-frags (m=d, k=key) are loaded DIRECTLY
// from global into registers (kf: dwordx4 gather over 16 rows; vf: dense
// 512B reads from key-tiled vt2) — no global_load_lds, no barriers, no
// fences (rounds 4-6: DMA slab pipeline either raced or serialized).
// Manual 1-tile-ahead ping-pong prefetch; compiler inserts vmcnt.
// Q pre-scaled by EXP_SCALE; P^T packed in-register (B-operand of K=16
// MFMA); O^T += V^T·P^T; cross-wave O/lsum reduction via LDS atomics.
// ---------------------------------------------------------------------------
__global__ __launch_bounds__(256, 2) void attn_fused(
    const unsigned short* __restrict__ qkv,   // (4096, 3072) bf16; Q*c [0,1024), K [1024,2048)
    const unsigned short* __restrict__ vt2,   // (32, 128, 64, 16) bf16 key-tiled V^T
    unsigned short* __restrict__ aout)        // (4096, 1024) bf16
{
  __shared__ float accS[4096];                 // O[q][d-swizzled] fp32
  __shared__ float lsumS[64];

  const int tid  = threadIdx.x;
  const int wave = tid >> 6, lane = tid & 63;
  const int quad = lane >> 4, l15 = lane & 15;
  const int id = blockIdx.x;
  // XCD-aware decode: all 32 q0-blocks of a bh-group land on one XCD ->
  // its 2MB K+V working set stays L2-resident.
  const int bh = (id & 7) * 4 + ((id >> 3) & 3);
  const int b = bh >> 4, h = bh & 15;
  const int q0 = (id >> 5) * 64;
  const size_t qkvB = (size_t)b * NSEQ * QKV_LD;

  // zero reduction buffers (ordered before any wave's epilogue atomics)
  for (int i = tid; i < 4096; i += 256) accS[i] = 0.f;
  if (tid < 64) lsumS[tid] = 0.f;
  __syncthreads();

  // Q fragments: all 64 q (B-operand: n=q=l15, k=d=ks*32+quad*8+j), in regs
  short8 qf[4][2];
#pragma unroll
  for (int qt = 0; qt < 4; ++qt)
#pragma unroll
    for (int ks = 0; ks < 2; ++ks)
      qf[qt][ks] = *(const short8*)(qkv + qkvB +
          (size_t)(q0 + qt * 16 + l15) * QKV_LD + h * HD + ks * 32 + quad * 8);

  // per-lane global bases
  const unsigned short* kA = qkv + qkvB + DIM + h * HD
      + (size_t)(wave * 16 + l15) * QKV_LD + quad * 8;          // kf0; kf1 = +32
  const unsigned short* vA = vt2 + (size_t)bh * 131072 + wave * 1024
      + l15 * 16 + quad * 4;                                    // + dt*256, + t*4096

  f32x4 oacc[4][4] = {};   // [dt][qt]: O^T[d=dt*16+quad*4+r][q=qt*16+l15]
  float lsum[4] = {};

  auto loadK = [&](int t, short8& o0, short8& o1) {
    const unsigned short* p = kA + (size_t)t * (64 * QKV_LD);
    o0 = *(const short8*)(p);
    o1 = *(const short8*)(p + 32);
  };
  auto loadV = [&](int t, short4v* o) {
    const unsigned short* p = vA + t * 4096;
#pragma unroll
    for (int dt = 0; dt < 4; ++dt)
      o[dt] = *(const short4v*)(p + dt * 256);
  };

  auto compute = [&](short8 kf0, short8 kf1, const short4v* vf) {
    f32x4 sacc[4] = {};
#pragma unroll
    for (int qt = 0; qt < 4; ++qt) {
      sacc[qt] = MFMA32(kf0, qf[qt][0], sacc[qt]);
      sacc[qt] = MFMA32(kf1, qf[qt][1], sacc[qt]);
    }
#pragma unroll
    for (int qt = 0; qt < 4; ++qt) {
      float p0 = EXP2(sacc[qt][0]);
      float p1 = EXP2(sacc[qt][1]);
      float p2 = EXP2(sacc[qt][2]);
      float p3 = EXP2(sacc[qt][3]);
      lsum[qt] += (p0 + p1) + (p2 + p3);
      unsigned r0 = __builtin_bit_cast(unsigned, p0) + 0x8000u;
      unsigned r1 = __builtin_bit_cast(unsigned, p1) + 0x8000u;
      unsigned r2 = __builtin_bit_cast(unsigned, p2) + 0x8000u;
      unsigned r3 = __builtin_bit_cast(unsigned, p3) + 0x8000u;
      uint2 pd;
      pd.x = __builtin_amdgcn_perm(r1, r0, 0x07060302u);
      pd.y = __builtin_amdgcn_perm(r3, r2, 0x07060302u);
      short4v pf = __builtin_bit_cast(short4v, pd);
#pragma unroll
      for (int dt = 0; dt < 4; ++dt)
        oacc[dt][qt] = MFMA16(vf[dt], pf, oacc[dt][qt]);
    }
  };

  // ping-pong prefetch: two register sets, no copies; load of set X re-issued
  // right after compute(X)'s last read, hidden under compute(Y).
  short8 k0a, k1a, k0b, k1b;
  short4v va[4], vb[4];
  loadK(0, k0a, k1a); loadV(0, va);
  loadK(1, k0b, k1b); loadV(1, vb);
  for (int i = 0; i < 15; ++i) {
    compute(k0a, k1a, va);
    loadK(2 * i + 2, k0a, k1a); loadV(2 * i + 2, va);
    compute(k0b, k1b, vb);
    loadK(2 * i + 3, k0b, k1b); loadV(2 * i + 3, vb);
  }
  compute(k0a, k1a, va);
  compute(k0b, k1b, vb);

  // cross-wave reduction: lsum then O partials
#pragma unroll
  for (int qt = 0; qt < 4; ++qt) {
    float s = lsum[qt];
    s += __shfl_xor(s, 16);
    s += __shfl_xor(s, 32);
    if (quad == 0) atomicAdd(&lsumS[qt * 16 + l15], s);
  }
#pragma unroll
  for (int dt = 0; dt < 4; ++dt)
#pragma unroll
    for (int qt = 0; qt < 4; ++qt) {
      int q = qt * 16 + l15;
      int dbase = dt * 16 + quad * 4;
#pragma unroll
      for (int r = 0; r < 4; ++r)
        atomicAdd(&accS[q * 64 + ((dbase + r + q) & 63)], oacc[dt][qt][r]);
    }
  __syncthreads();

  // store: wave w -> q rows w*16..+15; lane = d (coalesced 128B rows)
  const int d = lane;
  for (int qq = 0; qq < 16; ++qq) {
    int q = wave * 16 + qq;
    float inv = 1.0f / lsumS[q];
    float v = accS[q * 64 + ((d + q) & 63)] * inv;
    aout[(size_t)(b * NSEQ + q0 + q) * DIM + h * HD + d] = f2bf(v);
  }
}

// ---------------------------------------------------------------------------
extern "C" void kernel_launch(void* const* d_in, const int* in_sizes, int n_in,
                              void* d_out, int out_size, void* d_ws, size_t ws_size,
                              hipStream_t stream) {
  (void)in_sizes; (void)n_in; (void)out_size; (void)ws_size;
  const float* x      = (const float*)d_in[0];
  const float* qkv_w  = (const float*)d_in[1];
  const float* qkv_b  = (const float*)d_in[2];
  const float* proj_w = (const float*)d_in[3];
  const float* proj_b = (const float*)d_in[4];
  float* out = (float*)d_out;

  char* ws = (char*)d_ws;
  unsigned short* xb   = (unsigned short*)(ws);                       // 8 MB
  unsigned short* wqb  = (unsigned short*)(ws + ( 8u << 20));         // 6 MB
  unsigned short* wpb  = (unsigned short*)(ws + (14u << 20));         // 2 MB
  unsigned short* qkv  = (unsigned short*)(ws + (16u << 20));         // 24 MB
  unsigned short* vtw  = (unsigned short*)(ws + (40u << 20));         // 8 MB
  unsigned short* attn = (unsigned short*)(ws + (48u << 20));         // 8 MB

  cast_bf16_3<<<8192, 256, 0, stream>>>(x, qkv_w, proj_w, xb, wqb, wpb);
  gemm_nt<<<dim3(32, 24), 256, 0, stream>>>(xb, wqb, qkv_b, DIM, 1, qkv, vtw, nullptr);
  attn_fused<<<1024, 256, 0, stream>>>(qkv, vtw, attn);
  gemm_nt64<<<dim3(64, 8), 256, 0, stream>>>(attn, wpb, proj_b, DIM, out);
}

// Round 8
// 214.832 us; speedup vs baseline: 1.2685x; 1.2685x over previous
//
#include <hip/hip_runtime.h>

#define DIM 1024
#define NHEADS 16
#define HD 64
#define NSEQ 2048
#define MROWS 4096          // B*N
#define QKV_LD 3072

typedef __attribute__((ext_vector_type(8))) short short8;
typedef __attribute__((ext_vector_type(4))) short short4v;
typedef __attribute__((ext_vector_type(4))) float f32x4;

typedef __attribute__((address_space(1))) void gvoid_t;
typedef __attribute__((address_space(3))) void lvoid_t;

#if __has_builtin(__builtin_amdgcn_exp2f)
#define EXP2(x) __builtin_amdgcn_exp2f(x)
#else
#define EXP2(x) exp2f(x)
#endif

// K=16 bf16 MFMA: builtin name varies across ROCm versions; asm fallback.
#if __has_builtin(__builtin_amdgcn_mfma_f32_16x16x16_bf16)
#define MFMA16(a, b, c) __builtin_amdgcn_mfma_f32_16x16x16_bf16(a, b, c, 0, 0, 0)
#elif __has_builtin(__builtin_amdgcn_mfma_f32_16x16x16bf16_1k)
#define MFMA16(a, b, c) __builtin_amdgcn_mfma_f32_16x16x16bf16_1k(a, b, c, 0, 0, 0)
#else
static __device__ __forceinline__ f32x4 mfma16_asm(short4v a, short4v b, f32x4 c) {
  __asm__("v_mfma_f32_16x16x16_bf16 %0, %1, %2, %0" : "+v"(c) : "v"(a), "v"(b));
  return c;
}
#define MFMA16(a, b, c) mfma16_asm(a, b, c)
#endif

#define MFMA32(a, b, c) __builtin_amdgcn_mfma_f32_16x16x32_bf16(a, b, c, 0, 0, 0)

// exp2 arg scale: HEAD_DIM^-0.5 * log2(e)  (folded into Q at GEMM epilogue)
#define EXP_SCALE 0.18033688011112042f

__device__ __forceinline__ unsigned short f2bf(float f) {
  unsigned int u = __builtin_bit_cast(unsigned int, f);
  u += 0x7FFFu + ((u >> 16) & 1u);
  return (unsigned short)(u >> 16);
}

// async global->LDS, 16B per lane; LDS dst = wave-uniform base + lane*16
__device__ __forceinline__ void gl_lds16(const void* g, void* l) {
  __builtin_amdgcn_global_load_lds((gvoid_t*)g, (lvoid_t*)l, 16, 0, 0);
}

// ---------------------------------------------------------------------------
// Kernel 1: cast x (4M), qkv_w (3M), proj_w (1M) fp32 -> bf16. 2M float4 groups.
// ---------------------------------------------------------------------------
__global__ __launch_bounds__(256) void cast_bf16_3(
    const float* __restrict__ x, const float* __restrict__ wq,
    const float* __restrict__ wp,
    unsigned short* __restrict__ xb, unsigned short* __restrict__ wqb,
    unsigned short* __restrict__ wpb)
{
  int g = blockIdx.x * 256 + threadIdx.x;   // 0 .. 2097151
  const float* src;
  unsigned short* dst;
  if (g < 1048576)            { src = x  + (size_t)g * 4;              dst = xb  + (size_t)g * 4; }
  else if (g < 1048576 + 786432) { int t = g - 1048576; src = wq + (size_t)t * 4; dst = wqb + (size_t)t * 4; }
  else                        { int t = g - 1048576 - 786432; src = wp + (size_t)t * 4; dst = wpb + (size_t)t * 4; }
  float4 v = *(const float4*)src;
  ushort4 o;
  o.x = f2bf(v.x); o.y = f2bf(v.y); o.z = f2bf(v.z); o.w = f2bf(v.w);
  *(ushort4*)dst = o;
}

// ---------------------------------------------------------------------------
// Kernel 2: NT GEMM, 128x128x32 tile. mode 1: bf16 Q/K -> oq (ld 3072),
// Q columns pre-scaled by EXP_SCALE; V -> key-tiled V^T vt2[bh][n>>4][d][n&15].
// ---------------------------------------------------------------------------
__global__ __launch_bounds__(256) void gemm_nt(
    const unsigned short* __restrict__ A,
    const unsigned short* __restrict__ Bw,
    const float* __restrict__ bias,
    int K, int mode,
    unsigned short* __restrict__ oq,
    unsigned short* __restrict__ ovt,
    float* __restrict__ of)
{
  __shared__ unsigned short As[128 * 32];
  __shared__ unsigned short Bs[128 * 32];

  const int tid  = threadIdx.x;
  const int wave = tid >> 6, lane = tid & 63;
  const int quad = lane >> 4, l15 = lane & 15;
  const int mblk = blockIdx.x * 128;
  const int nblk = blockIdx.y * 128;
  const int wrow = (wave >> 1) * 64, wcol = (wave & 1) * 64;

  f32x4 acc[4][4] = {};

  const int sr = lane >> 2;                 // row within 16-row chunk
  const int sq = (lane & 3) ^ (sr & 3);     // swizzled k-chunk for this lane
  const unsigned short* aBase = A  + (size_t)(mblk + wave * 32 + sr) * K + sq * 8;
  const unsigned short* bBase = Bw + (size_t)(nblk + wave * 32 + sr) * K + sq * 8;

  for (int k0 = 0; k0 < K; k0 += 32) {
    __syncthreads();
    gl_lds16(aBase + k0,          As + (wave * 32) * 32);
    gl_lds16(aBase + 16 * K + k0, As + (wave * 32 + 16) * 32);
    gl_lds16(bBase + k0,          Bs + (wave * 32) * 32);
    gl_lds16(bBase + 16 * K + k0, Bs + (wave * 32 + 16) * 32);
    __syncthreads();

    short8 af[4], bf8[4];
#pragma unroll
    for (int mt = 0; mt < 4; ++mt) {
      int row = wrow + mt * 16 + l15;
      af[mt] = *(const short8*)(As + row * 32 + ((quad ^ (row & 3)) * 8));
    }
#pragma unroll
    for (int nt = 0; nt < 4; ++nt) {
      int row = wcol + nt * 16 + l15;
      bf8[nt] = *(const short8*)(Bs + row * 32 + ((quad ^ (row & 3)) * 8));
    }
#pragma unroll
    for (int mt = 0; mt < 4; ++mt)
#pragma unroll
      for (int nt = 0; nt < 4; ++nt)
        acc[mt][nt] = MFMA32(af[mt], bf8[nt], acc[mt][nt]);
  }

  float bv[4];
#pragma unroll
  for (int nt = 0; nt < 4; ++nt) bv[nt] = bias[nblk + wcol + nt * 16 + l15];

  if (mode == 0) {
#pragma unroll
    for (int mt = 0; mt < 4; ++mt) {
      int row0 = mblk + wrow + mt * 16 + quad * 4;
#pragma unroll
      for (int nt = 0; nt < 4; ++nt) {
        int col = nblk + wcol + nt * 16 + l15;
#pragma unroll
        for (int r = 0; r < 4; ++r)
          of[(size_t)(row0 + r) * DIM + col] = acc[mt][nt][r] + bv[nt];
      }
    }
  } else if (nblk < 2048) {
    // Q (pre-scaled by EXP_SCALE) or K block -> qkv buffer, bf16
    const float qs = (nblk < 1024) ? EXP_SCALE : 1.0f;
#pragma unroll
    for (int mt = 0; mt < 4; ++mt) {
      int row0 = mblk + wrow + mt * 16 + quad * 4;
#pragma unroll
      for (int nt = 0; nt < 4; ++nt) {
        int col = nblk + wcol + nt * 16 + l15;
#pragma unroll
        for (int r = 0; r < 4; ++r)
          oq[(size_t)(row0 + r) * QKV_LD + col] = f2bf((acc[mt][nt][r] + bv[nt]) * qs);
      }
    }
  } else {
    // V -> key-tiled transposed buffer: vt2[bh][n>>4][d][n&15]
#pragma unroll
    for (int mt = 0; mt < 4; ++mt) {
      int row0 = mblk + wrow + mt * 16 + quad * 4;
      int n0 = row0 & (NSEQ - 1);
      int bb = row0 >> 11;
#pragma unroll
      for (int nt = 0; nt < 4; ++nt) {
        int colr = (nblk - 2048) + wcol + nt * 16 + l15;
        int bh = bb * NHEADS + (colr >> 6);
        int d  = colr & 63;
        ushort4 pk;
        pk.x = f2bf(acc[mt][nt][0] + bv[nt]);
        pk.y = f2bf(acc[mt][nt][1] + bv[nt]);
        pk.z = f2bf(acc[mt][nt][2] + bv[nt]);
        pk.w = f2bf(acc[mt][nt][3] + bv[nt]);
        *(ushort4*)(ovt + (size_t)bh * 131072 + (n0 >> 4) * 1024 + d * 16 + (n0 & 15)) = pk;
      }
    }
  }
}

// ---------------------------------------------------------------------------
// Kernel 4: NT GEMM for proj: 64(M)x128(N)x32 tile -> 512 blocks (2/CU).
// ---------------------------------------------------------------------------
__global__ __launch_bounds__(256) void gemm_nt64(
    const unsigned short* __restrict__ A,
    const unsigned short* __restrict__ Bw,
    const float* __restrict__ bias,
    int K,
    float* __restrict__ of)
{
  __shared__ unsigned short As[64 * 32];
  __shared__ unsigned short Bs[128 * 32];

  const int tid  = threadIdx.x;
  const int wave = tid >> 6, lane = tid & 63;
  const int quad = lane >> 4, l15 = lane & 15;
  const int mblk = blockIdx.x * 64;
  const int nblk = blockIdx.y * 128;
  const int wrow = (wave >> 1) * 32, wcol = (wave & 1) * 64;

  f32x4 acc[2][4] = {};

  const int sr = lane >> 2;
  const int sq = (lane & 3) ^ (sr & 3);
  const unsigned short* aBase = A  + (size_t)(mblk + wave * 16 + sr) * K + sq * 8;
  const unsigned short* bBase = Bw + (size_t)(nblk + wave * 32 + sr) * K + sq * 8;

  for (int k0 = 0; k0 < K; k0 += 32) {
    __syncthreads();
    gl_lds16(aBase + k0,          As + (wave * 16) * 32);
    gl_lds16(bBase + k0,          Bs + (wave * 32) * 32);
    gl_lds16(bBase + 16 * K + k0, Bs + (wave * 32 + 16) * 32);
    __syncthreads();

    short8 af[2], bf8[4];
#pragma unroll
    for (int mt = 0; mt < 2; ++mt) {
      int row = wrow + mt * 16 + l15;
      af[mt] = *(const short8*)(As + row * 32 + ((quad ^ (row & 3)) * 8));
    }
#pragma unroll
    for (int nt = 0; nt < 4; ++nt) {
      int row = wcol + nt * 16 + l15;
      bf8[nt] = *(const short8*)(Bs + row * 32 + ((quad ^ (row & 3)) * 8));
    }
#pragma unroll
    for (int mt = 0; mt < 2; ++mt)
#pragma unroll
      for (int nt = 0; nt < 4; ++nt)
        acc[mt][nt] = MFMA32(af[mt], bf8[nt], acc[mt][nt]);
  }

  float bv[4];
#pragma unroll
  for (int nt = 0; nt < 4; ++nt) bv[nt] = bias[nblk + wcol + nt * 16 + l15];

#pragma unroll
  for (int mt = 0; mt < 2; ++mt) {
    int row0 = mblk + wrow + mt * 16 + quad * 4;
#pragma unroll
    for (int nt = 0; nt < 4; ++nt) {
      int col = nblk + wcol + nt * 16 + l15;
#pragma unroll
      for (int r = 0; r < 4; ++r)
        of[(size_t)(row0 + r) * DIM + col] = acc[mt][nt][r] + bv[nt];
    }
  }
}

// ---------------------------------------------------------------------------
// Kernel 3: fused attention — round-3 structure (best measured: 61 µs) with
// its two measured defects fixed:
//  * V never touches LDS: vf[dt][g] loaded straight from key-tiled vt2 into
//    registers (coalesced 512B/instr, r7-verified) — kills the 8.4M
//    ds_read_b64 bank conflicts r3 had.
//  * Q pre-scaled by EXP_SCALE in the GEMM epilogue (r6/7-verified).
// Block = (b,h) x 64 q, wave = 16 q (all keys). K tile (64x64) staged
// cooperatively via gl_lds16 + 2 barriers (r3-verified swizzle).
// S^T = K·Q^T; P^T packed in-register = B-operand of K=16 MFMA;
// O^T += V^T·P^T. No cross-wave reduction (wave owns its 16 q end-to-end).
// ---------------------------------------------------------------------------
__global__ __launch_bounds__(256, 2) void attn_fused(
    const unsigned short* __restrict__ qkv,   // (4096, 3072) bf16; Q*c [0,1024), K [1024,2048)
    const unsigned short* __restrict__ vt2,   // (32, 128, 64, 16) bf16 key-tiled V^T
    unsigned short* __restrict__ aout)        // (4096, 1024) bf16
{
  __shared__ unsigned short Ks[64 * 64];

  const int tid  = threadIdx.x;
  const int wave = tid >> 6, lane = tid & 63;
  const int quad = lane >> 4, l15 = lane & 15;
  const int bh = blockIdx.x, b = bh >> 4, h = bh & 15;
  const int q0 = blockIdx.y * 64;
  const size_t qkvB = (size_t)b * NSEQ * QKV_LD;

  // Q fragments (B-operand of S^T): lane n=q=l15, k=d=ks*32+quad*8+j
  short8 qf[2];
#pragma unroll
  for (int ks = 0; ks < 2; ++ks)
    qf[ks] = *(const short8*)(qkv + qkvB +
        (size_t)(q0 + wave * 16 + l15) * QKV_LD + h * HD + ks * 32 + quad * 8);

  f32x4 oacc[4] = {};      // O^T[d=dt*16+quad*4+r][q=l15]
  float lsum = 0.f;        // per-lane partial denominator for q=l15

  const int sr8 = lane >> 3;   // row within 8-row staging chunk
  const int sp8 = lane & 7;    // physical 16B chunk position
  const int sqc = sp8 ^ sr8;   // logical (global) chunk this lane stages

  const unsigned short* kBase = qkv + qkvB + DIM + h * HD;
  // per-lane V base: vf[dt][g] = vBase + t*4096 + g*1024 + dt*256
  const unsigned short* vBase = vt2 + (size_t)bh * 131072 + l15 * 16 + quad * 4;

  for (int t = 0; t < 32; ++t) {
    __syncthreads();   // WAR: all waves done reading Ks from previous tile
#pragma unroll
    for (int i = 0; i < 2; ++i) {
      int r = t * 64 + wave * 16 + i * 8 + sr8;
      gl_lds16(kBase + (size_t)r * QKV_LD + sqc * 8, Ks + (wave * 16 + i * 8) * 64);
    }
    // V fragments for this tile: straight global->register, issued before the
    // barrier so the barrier's vmcnt(0) drain covers both K-DMA and V.
    short4v vf[4][4];
#pragma unroll
    for (int dt = 0; dt < 4; ++dt)
#pragma unroll
      for (int g = 0; g < 4; ++g)
        vf[dt][g] = *(const short4v*)(vBase + t * 4096 + g * 1024 + dt * 256);
    __syncthreads();   // RAW: K tile visible

    // K A-frags: m=key=g*16+l15, k=d (swizzled chunks)
    short8 kf[4][2];
#pragma unroll
    for (int g = 0; g < 4; ++g)
#pragma unroll
      for (int ks = 0; ks < 2; ++ks) {
        int row = g * 16 + l15;
        kf[g][ks] = *(const short8*)(Ks + row * 64 + (((ks * 4 + quad) ^ (row & 7)) * 8));
      }

    // S^T = K·Q^T
    f32x4 sacc[4] = {};
#pragma unroll
    for (int g = 0; g < 4; ++g) {
      sacc[g] = MFMA32(kf[g][0], qf[0], sacc[g]);
      sacc[g] = MFMA32(kf[g][1], qf[1], sacc[g]);
    }

    // softmax (no max-sub; logits bounded, Q pre-scaled) + PV, in registers
#pragma unroll
    for (int g = 0; g < 4; ++g) {
      float p0 = EXP2(sacc[g][0]);
      float p1 = EXP2(sacc[g][1]);
      float p2 = EXP2(sacc[g][2]);
      float p3 = EXP2(sacc[g][3]);
      lsum += (p0 + p1) + (p2 + p3);
      unsigned r0 = __builtin_bit_cast(unsigned, p0) + 0x8000u;
      unsigned r1 = __builtin_bit_cast(unsigned, p1) + 0x8000u;
      unsigned r2 = __builtin_bit_cast(unsigned, p2) + 0x8000u;
      unsigned r3 = __builtin_bit_cast(unsigned, p3) + 0x8000u;
      uint2 pd;
      pd.x = __builtin_amdgcn_perm(r1, r0, 0x07060302u);  // {bf16(p1),bf16(p0)}
      pd.y = __builtin_amdgcn_perm(r3, r2, 0x07060302u);
      short4v pf = __builtin_bit_cast(short4v, pd);
#pragma unroll
      for (int dt = 0; dt < 4; ++dt)
        oacc[dt] = MFMA16(vf[dt][g], pf, oacc[dt]);
    }
  }

  // denominator: sum partials across the 4 quads holding the same q=l15
  lsum += __shfl_xor(lsum, 16);
  lsum += __shfl_xor(lsum, 32);
  float inv = 1.0f / lsum;

  const int qrow = q0 + wave * 16 + l15;
  const size_t outBase = (size_t)(b * NSEQ + qrow) * DIM + h * HD;
#pragma unroll
  for (int dt = 0; dt < 4; ++dt) {
    unsigned a0 = __builtin_bit_cast(unsigned, oacc[dt][0] * inv) + 0x8000u;
    unsigned a1 = __builtin_bit_cast(unsigned, oacc[dt][1] * inv) + 0x8000u;
    unsigned a2 = __builtin_bit_cast(unsigned, oacc[dt][2] * inv) + 0x8000u;
    unsigned a3 = __builtin_bit_cast(unsigned, oacc[dt][3] * inv) + 0x8000u;
    uint2 st;
    st.x = __builtin_amdgcn_perm(a1, a0, 0x07060302u);
    st.y = __builtin_amdgcn_perm(a3, a2, 0x07060302u);
    *(uint2*)(aout + outBase + dt * 16 + quad * 4) = st;
  }
}

// ---------------------------------------------------------------------------
extern "C" void kernel_launch(void* const* d_in, const int* in_sizes, int n_in,
                              void* d_out, int out_size, void* d_ws, size_t ws_size,
                              hipStream_t stream) {
  (void)in_sizes; (void)n_in; (void)out_size; (void)ws_size;
  const float* x      = (const float*)d_in[0];
  const float* qkv_w  = (const float*)d_in[1];
  const float* qkv_b  = (const float*)d_in[2];
  const float* proj_w = (const float*)d_in[3];
  const float* proj_b = (const float*)d_in[4];
  float* out = (float*)d_out;

  char* ws = (char*)d_ws;
  unsigned short* xb   = (unsigned short*)(ws);                       // 8 MB
  unsigned short* wqb  = (unsigned short*)(ws + ( 8u << 20));         // 6 MB
  unsigned short* wpb  = (unsigned short*)(ws + (14u << 20));         // 2 MB
  unsigned short* qkv  = (unsigned short*)(ws + (16u << 20));         // 24 MB
  unsigned short* vtw  = (unsigned short*)(ws + (40u << 20));         // 8 MB
  unsigned short* attn = (unsigned short*)(ws + (48u << 20));         // 8 MB

  cast_bf16_3<<<8192, 256, 0, stream>>>(x, qkv_w, proj_w, xb, wqb, wpb);
  gemm_nt<<<dim3(32, 24), 256, 0, stream>>>(xb, wqb, qkv_b, DIM, 1, qkv, vtw, nullptr);
  attn_fused<<<dim3(32, 32), 256, 0, stream>>>(qkv, vtw, attn);
  gemm_nt64<<<dim3(64, 8), 256, 0, stream>>>(attn, wpb, proj_b, DIM, out);
}